// Round 1
// baseline (109545.093 us; speedup 1.0000x reference)
//
#include <hip/hip_runtime.h>
#include <stdint.h>

// LSTM forward, B=32 T=2048 D=512 H=512 G=2048.
// Phase 1: prep  — convert x, w_ih to bf16; seed h_tag[0] from hx (tag 0).
// Phase 2: gemm  — gx[t][nw][b][g*16+jl] = x@w_ih^T + (b_ih+b_hh), bf16 in ws.
// Phase 3: rec   — 32 WGs (one per 16 h-cols), w_hh slice in VGPRs,
//                  per-step cross-WG h exchange via tagged dwords (bf16|step).

#define B_ 32
#define T_ 2048
#define D_ 512
#define H_ 512
#define G_ 2048
#define NW_ 32

typedef __attribute__((ext_vector_type(4))) float f32x4;
typedef __attribute__((ext_vector_type(8))) short bf16x8;
typedef __attribute__((ext_vector_type(4))) unsigned int uint4v;

__device__ __forceinline__ unsigned short f2bf(float f) {
  union { float f; unsigned int u; } v; v.f = f;
  unsigned int r = (v.u + 0x7FFFu + ((v.u >> 16) & 1u)) >> 16;
  return (unsigned short)r;
}
__device__ __forceinline__ float bf2f(unsigned short s) {
  union { unsigned int u; float f; } v; v.u = ((unsigned int)s) << 16;
  return v.f;
}
__device__ __forceinline__ float sigm(float x) { return 1.0f / (1.0f + __expf(-x)); }
__device__ __forceinline__ float tanh_(float x) { return 1.0f - 2.0f / (__expf(2.0f * x) + 1.0f); }

// ---------------- Phase 1: convert inputs ----------------
__global__ __launch_bounds__(256) void prep_kernel(
    const float* __restrict__ x, const float* __restrict__ w_ih,
    const float* __restrict__ hx,
    unsigned short* __restrict__ x_bf, unsigned short* __restrict__ w_bf,
    unsigned int* __restrict__ h_tag) {
  const int NX8 = (B_ * T_ * D_) / 8;   // 4,194,304
  const int NWT8 = (G_ * D_) / 8;       // 131,072
  int i = blockIdx.x * 256 + threadIdx.x;
  if (i < NX8) {
    float4 a = reinterpret_cast<const float4*>(x)[i * 2];
    float4 b = reinterpret_cast<const float4*>(x)[i * 2 + 1];
    uint4v v;
    v[0] = (unsigned)f2bf(a.x) | ((unsigned)f2bf(a.y) << 16);
    v[1] = (unsigned)f2bf(a.z) | ((unsigned)f2bf(a.w) << 16);
    v[2] = (unsigned)f2bf(b.x) | ((unsigned)f2bf(b.y) << 16);
    v[3] = (unsigned)f2bf(b.z) | ((unsigned)f2bf(b.w) << 16);
    reinterpret_cast<uint4v*>(x_bf)[i] = v;
  } else if (i < NX8 + NWT8) {
    int j = i - NX8;
    float4 a = reinterpret_cast<const float4*>(w_ih)[j * 2];
    float4 b = reinterpret_cast<const float4*>(w_ih)[j * 2 + 1];
    uint4v v;
    v[0] = (unsigned)f2bf(a.x) | ((unsigned)f2bf(a.y) << 16);
    v[1] = (unsigned)f2bf(a.z) | ((unsigned)f2bf(a.w) << 16);
    v[2] = (unsigned)f2bf(b.x) | ((unsigned)f2bf(b.y) << 16);
    v[3] = (unsigned)f2bf(b.z) | ((unsigned)f2bf(b.w) << 16);
    reinterpret_cast<uint4v*>(w_bf)[j] = v;
  } else {
    int j = i - NX8 - NWT8;  // < 2048, 8 hx elems each
    float4 a = reinterpret_cast<const float4*>(hx)[j * 2];
    float4 b = reinterpret_cast<const float4*>(hx)[j * 2 + 1];
    unsigned int* p = h_tag + j * 8;  // buffer 0, tag 0
    p[0] = f2bf(a.x); p[1] = f2bf(a.y); p[2] = f2bf(a.z); p[3] = f2bf(a.w);
    p[4] = f2bf(b.x); p[5] = f2bf(b.y); p[6] = f2bf(b.z); p[7] = f2bf(b.w);
  }
}

// ---------------- Phase 2: gx GEMM ----------------
// Rows r = b*2048+t (65536), cols = gcol (2048), K=512. 128x128 tile, BK=32,
// 4 waves each 64x64. Within a tile b and gate g are constant (2048%128==0,
// 512%128==0). Epilogue stages bf16 in LDS then writes 32B runs to
// gx_ws[t][nw][b][g*16+jl].
__global__ __launch_bounds__(256, 2) void gemm_gx(
    const unsigned short* __restrict__ x_bf, const unsigned short* __restrict__ w_bf,
    const float* __restrict__ b_ih, const float* __restrict__ b_hh,
    unsigned short* __restrict__ gx_ws) {
  __shared__ unsigned short As[128 * 40];   // pad 32->40 to spread banks
  __shared__ unsigned short Bs[128 * 40];
  __shared__ unsigned short Eg[128 * 136];  // epilogue staging, pad 128->136
  const int bid = blockIdx.x;
  const int cb = bid & 15, rb = bid >> 4;
  const int r0 = rb * 128, c0 = cb * 128;
  const int tid = threadIdx.x;
  const int lane = tid & 63;
  const int w = tid >> 6;
  const int qr = (w >> 1) * 64, qc = (w & 1) * 64;
  f32x4 acc[4][4] = {};

  for (int kt = 0; kt < 16; ++kt) {
    const int k0 = kt * 32;
    uint4v av[2], bv[2];
#pragma unroll
    for (int c = 0; c < 2; ++c) {
      int flat = c * 256 + tid;
      int row = flat >> 2, q = flat & 3;
      av[c] = *reinterpret_cast<const uint4v*>(x_bf + (size_t)(r0 + row) * 512 + k0 + q * 8);
      bv[c] = *reinterpret_cast<const uint4v*>(w_bf + (size_t)(c0 + row) * 512 + k0 + q * 8);
    }
    __syncthreads();
#pragma unroll
    for (int c = 0; c < 2; ++c) {
      int flat = c * 256 + tid;
      int row = flat >> 2, q = flat & 3;
      *reinterpret_cast<uint4v*>(&As[row * 40 + q * 8]) = av[c];
      *reinterpret_cast<uint4v*>(&Bs[row * 40 + q * 8]) = bv[c];
    }
    __syncthreads();
    bf16x8 af[4], bfr[4];
#pragma unroll
    for (int mt = 0; mt < 4; ++mt)
      af[mt] = *reinterpret_cast<const bf16x8*>(&As[(qr + mt * 16 + (lane & 15)) * 40 + (lane >> 4) * 8]);
#pragma unroll
    for (int nt = 0; nt < 4; ++nt)
      bfr[nt] = *reinterpret_cast<const bf16x8*>(&Bs[(qc + nt * 16 + (lane & 15)) * 40 + (lane >> 4) * 8]);
#pragma unroll
    for (int mt = 0; mt < 4; ++mt)
#pragma unroll
      for (int nt = 0; nt < 4; ++nt)
        acc[mt][nt] = __builtin_amdgcn_mfma_f32_16x16x32_bf16(af[mt], bfr[nt], acc[mt][nt], 0, 0, 0);
  }
  __syncthreads();
  // bias + stage to Eg (C/D layout: col=lane&15, row=(lane>>4)*4+j)
#pragma unroll
  for (int nt = 0; nt < 4; ++nt) {
    int cg = c0 + qc + nt * 16 + (lane & 15);
    float bias = b_ih[cg] + b_hh[cg];
#pragma unroll
    for (int mt = 0; mt < 4; ++mt)
#pragma unroll
      for (int j = 0; j < 4; ++j) {
        int tr = qr + mt * 16 + (lane >> 4) * 4 + j;
        int cl = qc + nt * 16 + (lane & 15);
        Eg[tr * 136 + cl] = f2bf(acc[mt][nt][j] + bias);
      }
  }
  __syncthreads();
  const int b = r0 >> 11;          // batch, constant per tile
  const int g = c0 >> 9;           // gate, constant per tile
  const int t0 = r0 & 2047;
  const int nw0 = (c0 & 511) >> 4;
  for (int c = tid; c < 1024; c += 256) {
    int tr = c >> 3, nwi = c & 7;
    size_t dst = ((size_t)(t0 + tr) * NW_ + (nw0 + nwi)) * 2048 + b * 64 + g * 16;
    uint4v v0 = *reinterpret_cast<const uint4v*>(&Eg[tr * 136 + nwi * 16]);
    uint4v v1 = *reinterpret_cast<const uint4v*>(&Eg[tr * 136 + nwi * 16 + 8]);
    *reinterpret_cast<uint4v*>(gx_ws + dst) = v0;
    *reinterpret_cast<uint4v*>(gx_ws + dst + 8) = v1;
  }
}

// ---------------- Phase 3: recurrence ----------------
// 32 WGs x 512 threads (8 waves). WG nw owns h-cols [nw*16, nw*16+16).
// Wave (mt=w>>2, gate=w&3): one 16x16x32 MFMA chain over K=512.
// h exchanged as dwords (low16 = bf16 h, high16 = step tag), double-buffered.
__global__ __launch_bounds__(512, 2) void lstm_rec(
    const float* __restrict__ cx, const float* __restrict__ w_hh,
    const unsigned short* __restrict__ gx_ws, unsigned int* __restrict__ h_tag,
    float* __restrict__ out) {
  const int nw = blockIdx.x;
  const int tid = threadIdx.x;
  const int lane = tid & 63;
  const int w = tid >> 6;
  const int mt = w >> 2;
  const int g = w & 3;
  __shared__ unsigned short As[32 * 520];  // h tile, pad 512->520
  __shared__ float Gt[32 * 64];            // raw MFMA gates
  __shared__ unsigned short Gx[32 * 64];   // gx chunk (bf16)

  // w_hh slice -> registers (16 bf16x8 frags = 64 VGPR)
  bf16x8 breg[16];
  {
    const int gcol = g * 512 + nw * 16 + (lane & 15);
    const float* wrow = w_hh + (size_t)gcol * 512;
#pragma unroll
    for (int kk = 0; kk < 16; ++kk) {
      int k = kk * 32 + (lane >> 4) * 8;
      float4 f0 = *reinterpret_cast<const float4*>(wrow + k);
      float4 f1 = *reinterpret_cast<const float4*>(wrow + k + 4);
      uint4v v;
      v[0] = (unsigned)f2bf(f0.x) | ((unsigned)f2bf(f0.y) << 16);
      v[1] = (unsigned)f2bf(f0.z) | ((unsigned)f2bf(f0.w) << 16);
      v[2] = (unsigned)f2bf(f1.x) | ((unsigned)f2bf(f1.y) << 16);
      v[3] = (unsigned)f2bf(f1.z) | ((unsigned)f2bf(f1.w) << 16);
      breg[kk] = __builtin_bit_cast(bf16x8, v);
    }
  }
  // elementwise ownership: one (b, jl) pair per thread
  const int eb = tid >> 4;
  const int jl = tid & 15;
  const int jh = nw * 16 + jl;
  float c = cx[eb * 512 + jh];
  // poll ownership: 32 contiguous words of one batch row
  const int pb = tid >> 4;
  const int pj0 = (tid & 15) * 32;

  const unsigned short* gx_base = gx_ws + (size_t)nw * 2048;
  uint4v gxv = *reinterpret_cast<const uint4v*>(gx_base + (size_t)0 * 65536 + tid * 8);

  for (int t = 0; t < T_; ++t) {
    // ---- poll h (want tag == t), buffer t&1; write into As
    {
      unsigned int* hp = h_tag + (t & 1) * 16384 + pb * 512 + pj0;
      const unsigned int want = (unsigned int)t;
      unsigned int hv[32];
#pragma unroll
      for (int i = 0; i < 32; ++i)
        hv[i] = __hip_atomic_load(hp + i, __ATOMIC_RELAXED, __HIP_MEMORY_SCOPE_AGENT);
#pragma unroll
      for (int i = 0; i < 32; ++i) {
        int guard = 0;
        while ((hv[i] >> 16) != want) {
          __builtin_amdgcn_s_sleep(2);
          __builtin_amdgcn_fence(__ATOMIC_ACQUIRE, "agent");
          hv[i] = __hip_atomic_load(hp + i, __ATOMIC_RELAXED, __HIP_MEMORY_SCOPE_AGENT);
          if (++guard > (1 << 20)) break;  // bail to absmax-fail instead of hang
        }
      }
#pragma unroll
      for (int q = 0; q < 4; ++q) {
        uint4v v;
        v[0] = (hv[q * 8 + 0] & 0xffffu) | (hv[q * 8 + 1] << 16);
        v[1] = (hv[q * 8 + 2] & 0xffffu) | (hv[q * 8 + 3] << 16);
        v[2] = (hv[q * 8 + 4] & 0xffffu) | (hv[q * 8 + 5] << 16);
        v[3] = (hv[q * 8 + 6] & 0xffffu) | (hv[q * 8 + 7] << 16);
        *reinterpret_cast<uint4v*>(&As[pb * 520 + pj0 + q * 8]) = v;
      }
    }
    *reinterpret_cast<uint4v*>(&Gx[tid * 8]) = gxv;
    if (t + 1 < T_)
      gxv = *reinterpret_cast<const uint4v*>(gx_base + (size_t)(t + 1) * 65536 + tid * 8);
    __syncthreads();
    // ---- MFMA: gates[mt*16.., g*16..] over K=512
    f32x4 acc = {};
#pragma unroll
    for (int kk = 0; kk < 16; ++kk) {
      bf16x8 af = *reinterpret_cast<const bf16x8*>(
          &As[(mt * 16 + (lane & 15)) * 520 + kk * 32 + (lane >> 4) * 8]);
      acc = __builtin_amdgcn_mfma_f32_16x16x32_bf16(af, breg[kk], acc, 0, 0, 0);
    }
#pragma unroll
    for (int j = 0; j < 4; ++j)
      Gt[(mt * 16 + (lane >> 4) * 4 + j) * 64 + g * 16 + (lane & 15)] = acc[j];
    __syncthreads();
    // ---- elementwise + outputs + h publish
    {
      float iv = Gt[eb * 64 + jl]      + bf2f(Gx[eb * 64 + jl]);
      float fv = Gt[eb * 64 + 16 + jl] + bf2f(Gx[eb * 64 + 16 + jl]);
      float gv = Gt[eb * 64 + 32 + jl] + bf2f(Gx[eb * 64 + 32 + jl]);
      float ov = Gt[eb * 64 + 48 + jl] + bf2f(Gx[eb * 64 + 48 + jl]);
      float ia = sigm(iv), fa = sigm(fv), ga = tanh_(gv), oa = sigm(ov);
      c = fa * c + ia * ga;
      float h = oa * tanh_(c);
      size_t bo = (size_t)eb * (T_ * H_) + (size_t)t * H_ + jh;
      out[bo] = fa;                              // forgetgates
      out[(size_t)B_ * T_ * H_ + bo] = h;        // hiddens
      out[(size_t)2 * B_ * T_ * H_ + bo] = ga;   // cellgates
      if (t == T_ - 1) out[(size_t)3 * B_ * T_ * H_ + eb * H_ + jh] = oa;  // outgate_last
      unsigned int word = (unsigned int)f2bf(h) | (((unsigned int)(t + 1)) << 16);
      __hip_atomic_store(h_tag + ((t + 1) & 1) * 16384 + eb * 512 + jh, word,
                         __ATOMIC_RELAXED, __HIP_MEMORY_SCOPE_AGENT);
    }
    // belt: push dirty lines (no-op if sc1 stores write through)
    __builtin_amdgcn_fence(__ATOMIC_RELEASE, "agent");
    __syncthreads();
  }
}

extern "C" void kernel_launch(void* const* d_in, const int* in_sizes, int n_in,
                              void* d_out, int out_size, void* d_ws, size_t ws_size,
                              hipStream_t stream) {
  const float* x    = (const float*)d_in[0];
  const float* hx   = (const float*)d_in[1];
  const float* cx   = (const float*)d_in[2];
  const float* w_ih = (const float*)d_in[3];
  const float* w_hh = (const float*)d_in[4];
  const float* b_ih = (const float*)d_in[5];
  const float* b_hh = (const float*)d_in[6];
  float* out = (float*)d_out;
  char* ws = (char*)d_ws;
  // ws layout (bytes)
  const size_t OFF_XBF  = 0;                    // 67,108,864
  const size_t OFF_WBF  = 67108864;             //  2,097,152
  const size_t OFF_GX   = 69206016;             // 268,435,456
  const size_t OFF_HTAG = 337641472;            //    131,072
  const size_t NEEDED   = 337772544;
  if (ws_size < NEEDED) return;  // distinctive failure (zeros) if ws too small

  unsigned short* x_bf  = (unsigned short*)(ws + OFF_XBF);
  unsigned short* w_bf  = (unsigned short*)(ws + OFF_WBF);
  unsigned short* gx_ws = (unsigned short*)(ws + OFF_GX);
  unsigned int*   h_tag = (unsigned int*)(ws + OFF_HTAG);

  hipMemsetAsync(h_tag, 0, 131072, stream);               // clear tags every replay
  prep_kernel<<<16904, 256, 0, stream>>>(x, w_ih, hx, x_bf, w_bf, h_tag);
  gemm_gx<<<8192, 256, 0, stream>>>(x_bf, w_bf, b_ih, b_hh, gx_ws);
  lstm_rec<<<32, 512, 0, stream>>>(cx, w_hh, gx_ws, h_tag, out);
}

// Round 3
// 9781.613 us; speedup vs baseline: 11.1991x; 11.1991x over previous
//
#include <hip/hip_runtime.h>
#include <stdint.h>

// LSTM forward, B=32 T=2048 D=512 H=512 G=2048.
// Phase 1: prep  — convert x, w_ih to bf16; seed h_tag slot0 from hx (tag 0,
//                  sc0sc1 stores); clear h_tag slot1 (sc0sc1 stores).
// Phase 2: gemm  — gx[t][nw][b][g*16+jl] = x@w_ih^T + (b_ih+b_hh), bf16 in ws.
// Phase 3: rec   — 32 WGs (one per 16 h-cols), w_hh slice in VGPRs,
//                  per-step cross-WG h exchange via tagged dwords
//                  (low16 = bf16 h, high16 = step tag), double-buffered.
//                  ALL h_tag traffic uses explicit sc0 sc1 (MALL-coherent,
//                  bypasses non-coherent per-XCD L2) — no fences needed since
//                  tag and payload share one word.

#define B_ 32
#define T_ 2048
#define D_ 512
#define H_ 512
#define G_ 2048
#define NW_ 32

typedef __attribute__((ext_vector_type(4))) float f32x4;
typedef __attribute__((ext_vector_type(8))) short bf16x8;
typedef __attribute__((ext_vector_type(4))) unsigned int uint4v;

__device__ __forceinline__ unsigned short f2bf(float f) {
  union { float f; unsigned int u; } v; v.f = f;
  unsigned int r = (v.u + 0x7FFFu + ((v.u >> 16) & 1u)) >> 16;
  return (unsigned short)r;
}
__device__ __forceinline__ float bf2f(unsigned short s) {
  union { unsigned int u; float f; } v; v.u = ((unsigned int)s) << 16;
  return v.f;
}
__device__ __forceinline__ float sigm(float x) { return 1.0f / (1.0f + __expf(-x)); }
__device__ __forceinline__ float tanh_(float x) { return 1.0f - 2.0f / (__expf(2.0f * x) + 1.0f); }

// MALL-coherent (cross-XCD) accesses: explicit sc0 sc1 cache bits.
__device__ __forceinline__ void store_x4_coherent(unsigned int* p, uint4v v) {
  asm volatile("global_store_dwordx4 %0, %1, off sc0 sc1" :: "v"(p), "v"(v) : "memory");
}
__device__ __forceinline__ void store_x2_coherent(unsigned long long* p, unsigned long long v) {
  asm volatile("global_store_dwordx2 %0, %1, off sc0 sc1" :: "v"(p), "v"(v) : "memory");
}

// ---------------- Phase 1: convert inputs + seed/clear h_tag ----------------
__global__ __launch_bounds__(256) void prep_kernel(
    const float* __restrict__ x, const float* __restrict__ w_ih,
    const float* __restrict__ hx,
    unsigned short* __restrict__ x_bf, unsigned short* __restrict__ w_bf,
    unsigned int* __restrict__ h_tag) {
  const int NX8 = (B_ * T_ * D_) / 8;   // 4,194,304
  const int NWT8 = (G_ * D_) / 8;       // 131,072
  int i = blockIdx.x * 256 + threadIdx.x;
  if (i < NX8) {
    float4 a = reinterpret_cast<const float4*>(x)[i * 2];
    float4 b = reinterpret_cast<const float4*>(x)[i * 2 + 1];
    uint4v v;
    v[0] = (unsigned)f2bf(a.x) | ((unsigned)f2bf(a.y) << 16);
    v[1] = (unsigned)f2bf(a.z) | ((unsigned)f2bf(a.w) << 16);
    v[2] = (unsigned)f2bf(b.x) | ((unsigned)f2bf(b.y) << 16);
    v[3] = (unsigned)f2bf(b.z) | ((unsigned)f2bf(b.w) << 16);
    reinterpret_cast<uint4v*>(x_bf)[i] = v;
  } else if (i < NX8 + NWT8) {
    int j = i - NX8;
    float4 a = reinterpret_cast<const float4*>(w_ih)[j * 2];
    float4 b = reinterpret_cast<const float4*>(w_ih)[j * 2 + 1];
    uint4v v;
    v[0] = (unsigned)f2bf(a.x) | ((unsigned)f2bf(a.y) << 16);
    v[1] = (unsigned)f2bf(a.z) | ((unsigned)f2bf(a.w) << 16);
    v[2] = (unsigned)f2bf(b.x) | ((unsigned)f2bf(b.y) << 16);
    v[3] = (unsigned)f2bf(b.z) | ((unsigned)f2bf(b.w) << 16);
    reinterpret_cast<uint4v*>(w_bf)[j] = v;
  } else if (i < NX8 + NWT8 + 2048) {
    int j = i - NX8 - NWT8;  // seed slot 0 from hx, tag 0
    float4 a = reinterpret_cast<const float4*>(hx)[j * 2];
    float4 b = reinterpret_cast<const float4*>(hx)[j * 2 + 1];
    uint4v v0, v1;
    v0[0] = f2bf(a.x); v0[1] = f2bf(a.y); v0[2] = f2bf(a.z); v0[3] = f2bf(a.w);
    v1[0] = f2bf(b.x); v1[1] = f2bf(b.y); v1[2] = f2bf(b.z); v1[3] = f2bf(b.w);
    unsigned int* p = h_tag + j * 8;
    store_x4_coherent(p, v0);
    store_x4_coherent(p + 4, v1);
  } else {
    int j = i - NX8 - NWT8 - 2048;  // clear slot 1
    unsigned int* p = h_tag + 16384 + j * 8;
    uint4v z = {0u, 0u, 0u, 0u};
    store_x4_coherent(p, z);
    store_x4_coherent(p + 4, z);
  }
}

// ---------------- Phase 2: gx GEMM ----------------
// Rows r = b*2048+t (65536), cols = gcol (2048), K=512. 128x128 tile, BK=32,
// 4 waves each 64x64. Epilogue stages bf16 in LDS then writes 32B runs to
// gx_ws[t][nw][b][g*16+jl].
__global__ __launch_bounds__(256, 2) void gemm_gx(
    const unsigned short* __restrict__ x_bf, const unsigned short* __restrict__ w_bf,
    const float* __restrict__ b_ih, const float* __restrict__ b_hh,
    unsigned short* __restrict__ gx_ws) {
  __shared__ unsigned short As[128 * 40];   // pad 32->40 to spread banks
  __shared__ unsigned short Bs[128 * 40];
  __shared__ unsigned short Eg[128 * 136];  // epilogue staging, pad 128->136
  const int bid = blockIdx.x;
  const int cb = bid & 15, rb = bid >> 4;
  const int r0 = rb * 128, c0 = cb * 128;
  const int tid = threadIdx.x;
  const int lane = tid & 63;
  const int w = tid >> 6;
  const int qr = (w >> 1) * 64, qc = (w & 1) * 64;
  f32x4 acc[4][4] = {};

  for (int kt = 0; kt < 16; ++kt) {
    const int k0 = kt * 32;
    uint4v av[2], bv[2];
#pragma unroll
    for (int c = 0; c < 2; ++c) {
      int flat = c * 256 + tid;
      int row = flat >> 2, q = flat & 3;
      av[c] = *reinterpret_cast<const uint4v*>(x_bf + (size_t)(r0 + row) * 512 + k0 + q * 8);
      bv[c] = *reinterpret_cast<const uint4v*>(w_bf + (size_t)(c0 + row) * 512 + k0 + q * 8);
    }
    __syncthreads();
#pragma unroll
    for (int c = 0; c < 2; ++c) {
      int flat = c * 256 + tid;
      int row = flat >> 2, q = flat & 3;
      *reinterpret_cast<uint4v*>(&As[row * 40 + q * 8]) = av[c];
      *reinterpret_cast<uint4v*>(&Bs[row * 40 + q * 8]) = bv[c];
    }
    __syncthreads();
    bf16x8 af[4], bfr[4];
#pragma unroll
    for (int mt = 0; mt < 4; ++mt)
      af[mt] = *reinterpret_cast<const bf16x8*>(&As[(qr + mt * 16 + (lane & 15)) * 40 + (lane >> 4) * 8]);
#pragma unroll
    for (int nt = 0; nt < 4; ++nt)
      bfr[nt] = *reinterpret_cast<const bf16x8*>(&Bs[(qc + nt * 16 + (lane & 15)) * 40 + (lane >> 4) * 8]);
#pragma unroll
    for (int mt = 0; mt < 4; ++mt)
#pragma unroll
      for (int nt = 0; nt < 4; ++nt)
        acc[mt][nt] = __builtin_amdgcn_mfma_f32_16x16x32_bf16(af[mt], bfr[nt], acc[mt][nt], 0, 0, 0);
  }
  __syncthreads();
  // bias + stage to Eg (C/D layout: col=lane&15, row=(lane>>4)*4+j)
#pragma unroll
  for (int nt = 0; nt < 4; ++nt) {
    int cg = c0 + qc + nt * 16 + (lane & 15);
    float bias = b_ih[cg] + b_hh[cg];
#pragma unroll
    for (int mt = 0; mt < 4; ++mt)
#pragma unroll
      for (int j = 0; j < 4; ++j) {
        int tr = qr + mt * 16 + (lane >> 4) * 4 + j;
        int cl = qc + nt * 16 + (lane & 15);
        Eg[tr * 136 + cl] = f2bf(acc[mt][nt][j] + bias);
      }
  }
  __syncthreads();
  const int b = r0 >> 11;          // batch, constant per tile
  const int g = c0 >> 9;           // gate, constant per tile
  const int t0 = r0 & 2047;
  const int nw0 = (c0 & 511) >> 4;
  for (int c = tid; c < 1024; c += 256) {
    int tr = c >> 3, nwi = c & 7;
    size_t dst = ((size_t)(t0 + tr) * NW_ + (nw0 + nwi)) * 2048 + b * 64 + g * 16;
    uint4v v0 = *reinterpret_cast<const uint4v*>(&Eg[tr * 136 + nwi * 16]);
    uint4v v1 = *reinterpret_cast<const uint4v*>(&Eg[tr * 136 + nwi * 16 + 8]);
    *reinterpret_cast<uint4v*>(gx_ws + dst) = v0;
    *reinterpret_cast<uint4v*>(gx_ws + dst + 8) = v1;
  }
}

// ---------------- Phase 3: recurrence ----------------
// 32 WGs x 512 threads (8 waves). WG nw owns h-cols [nw*16, nw*16+16).
// Wave (mt=w>>2, gate=w&3): one 16x16x32 MFMA chain over K=512.
__global__ __launch_bounds__(512, 2) void lstm_rec(
    const float* __restrict__ cx, const float* __restrict__ w_hh,
    const unsigned short* __restrict__ gx_ws, unsigned int* __restrict__ h_tag,
    float* __restrict__ out) {
  const int nw = blockIdx.x;
  const int tid = threadIdx.x;
  const int lane = tid & 63;
  const int w = tid >> 6;
  const int mt = w >> 2;
  const int g = w & 3;
  __shared__ unsigned short As[32 * 520];  // h tile, pad 512->520
  __shared__ float Gt[32 * 64];            // raw MFMA gates
  __shared__ unsigned short Gx[32 * 64];   // gx chunk (bf16)

  // w_hh slice -> registers (16 bf16x8 frags = 64 VGPR)
  bf16x8 breg[16];
  {
    const int gcol = g * 512 + nw * 16 + (lane & 15);
    const float* wrow = w_hh + (size_t)gcol * 512;
#pragma unroll
    for (int kk = 0; kk < 16; ++kk) {
      int k = kk * 32 + (lane >> 4) * 8;
      float4 f0 = *reinterpret_cast<const float4*>(wrow + k);
      float4 f1 = *reinterpret_cast<const float4*>(wrow + k + 4);
      uint4v v;
      v[0] = (unsigned)f2bf(f0.x) | ((unsigned)f2bf(f0.y) << 16);
      v[1] = (unsigned)f2bf(f0.z) | ((unsigned)f2bf(f0.w) << 16);
      v[2] = (unsigned)f2bf(f1.x) | ((unsigned)f2bf(f1.y) << 16);
      v[3] = (unsigned)f2bf(f1.z) | ((unsigned)f2bf(f1.w) << 16);
      breg[kk] = __builtin_bit_cast(bf16x8, v);
    }
  }
  // elementwise ownership: one (b, jl) pair per thread
  const int eb = tid >> 4;
  const int jl = tid & 15;
  const int jh = nw * 16 + jl;
  float c = cx[eb * 512 + jh];
  // poll ownership: 32 contiguous dwords of one batch row
  const int pb = tid >> 4;
  const int pj0 = (tid & 15) * 32;

  const unsigned short* gx_base = gx_ws + (size_t)nw * 2048;
  uint4v gxv = *reinterpret_cast<const uint4v*>(gx_base + (size_t)0 * 65536 + tid * 8);

  for (int t = 0; t < T_; ++t) {
    // ---- poll h (want tag == t), buffer t&1; batched sc0sc1 load rounds
    {
      const unsigned int* hp = h_tag + (t & 1) * 16384 + pb * 512 + pj0;
      const unsigned int want = (unsigned int)t;
      uint4v hv[8];
      for (int round = 0;; ++round) {
#define PLOAD(i, offs) \
        asm volatile("global_load_dwordx4 %0, %1, off offset:" #offs " sc0 sc1" \
                     : "=v"(hv[i]) : "v"(hp));
        PLOAD(0, 0) PLOAD(1, 16) PLOAD(2, 32) PLOAD(3, 48)
        PLOAD(4, 64) PLOAD(5, 80) PLOAD(6, 96) PLOAD(7, 112)
#undef PLOAD
        asm volatile("s_waitcnt vmcnt(0)" ::: "memory");
        __builtin_amdgcn_sched_barrier(0);
        bool ok = true;
#pragma unroll
        for (int i = 0; i < 8; ++i)
#pragma unroll
          for (int k = 0; k < 4; ++k)
            ok &= ((hv[i][k] >> 16) == want);
        if (ok) break;
        if (round > (1 << 18)) break;  // bounded bail (absmax-fail, not hang)
      }
#pragma unroll
      for (int q = 0; q < 4; ++q) {
        uint4v v;
        v[0] = (hv[2 * q][0] & 0xffffu)     | (hv[2 * q][1] << 16);
        v[1] = (hv[2 * q][2] & 0xffffu)     | (hv[2 * q][3] << 16);
        v[2] = (hv[2 * q + 1][0] & 0xffffu) | (hv[2 * q + 1][1] << 16);
        v[3] = (hv[2 * q + 1][2] & 0xffffu) | (hv[2 * q + 1][3] << 16);
        *reinterpret_cast<uint4v*>(&As[pb * 520 + pj0 + q * 8]) = v;
      }
    }
    *reinterpret_cast<uint4v*>(&Gx[tid * 8]) = gxv;
    if (t + 1 < T_)
      gxv = *reinterpret_cast<const uint4v*>(gx_base + (size_t)(t + 1) * 65536 + tid * 8);
    __syncthreads();
    // ---- MFMA: gates[mt*16.., g*16..] over K=512
    f32x4 acc = {};
#pragma unroll
    for (int kk = 0; kk < 16; ++kk) {
      bf16x8 af = *reinterpret_cast<const bf16x8*>(
          &As[(mt * 16 + (lane & 15)) * 520 + kk * 32 + (lane >> 4) * 8]);
      acc = __builtin_amdgcn_mfma_f32_16x16x32_bf16(af, breg[kk], acc, 0, 0, 0);
    }
#pragma unroll
    for (int j = 0; j < 4; ++j)
      Gt[(mt * 16 + (lane >> 4) * 4 + j) * 64 + g * 16 + (lane & 15)] = acc[j];
    __syncthreads();
    // ---- elementwise: publish h FIRST (critical path), then out stores
    {
      float iv = Gt[eb * 64 + jl]      + bf2f(Gx[eb * 64 + jl]);
      float fv = Gt[eb * 64 + 16 + jl] + bf2f(Gx[eb * 64 + 16 + jl]);
      float gv = Gt[eb * 64 + 32 + jl] + bf2f(Gx[eb * 64 + 32 + jl]);
      float ov = Gt[eb * 64 + 48 + jl] + bf2f(Gx[eb * 64 + 48 + jl]);
      float ia = sigm(iv), fa = sigm(fv), ga = tanh_(gv), oa = sigm(ov);
      c = fa * c + ia * ga;
      float h = oa * tanh_(c);
      // publish: pack 2 neighboring cols into one 64-bit sc0sc1 store
      unsigned int word = (unsigned int)f2bf(h) | (((unsigned int)(t + 1)) << 16);
      unsigned int pw = __shfl_xor(word, 1);
      if (!(tid & 1)) {
        unsigned long long dw = ((unsigned long long)pw << 32) | (unsigned long long)word;
        store_x2_coherent(
            (unsigned long long*)(h_tag + ((t + 1) & 1) * 16384 + eb * 512 + jh), dw);
      }
      size_t bo = (size_t)eb * (T_ * H_) + (size_t)t * H_ + jh;
      out[bo] = fa;                              // forgetgates
      out[(size_t)B_ * T_ * H_ + bo] = h;        // hiddens
      out[(size_t)2 * B_ * T_ * H_ + bo] = ga;   // cellgates
      if (t == T_ - 1) out[(size_t)3 * B_ * T_ * H_ + eb * H_ + jh] = oa;  // outgate_last
    }
    __syncthreads();  // protect As/Gx/Gt for next iteration's overwrite
  }
}

extern "C" void kernel_launch(void* const* d_in, const int* in_sizes, int n_in,
                              void* d_out, int out_size, void* d_ws, size_t ws_size,
                              hipStream_t stream) {
  const float* x    = (const float*)d_in[0];
  const float* hx   = (const float*)d_in[1];
  const float* cx   = (const float*)d_in[2];
  const float* w_ih = (const float*)d_in[3];
  const float* w_hh = (const float*)d_in[4];
  const float* b_ih = (const float*)d_in[5];
  const float* b_hh = (const float*)d_in[6];
  float* out = (float*)d_out;
  char* ws = (char*)d_ws;
  // ws layout (bytes)
  const size_t OFF_XBF  = 0;                    // 67,108,864
  const size_t OFF_WBF  = 67108864;             //  2,097,152
  const size_t OFF_GX   = 69206016;             // 268,435,456
  const size_t OFF_HTAG = 337641472;            //    131,072
  const size_t NEEDED   = 337772544;
  if (ws_size < NEEDED) return;  // distinctive failure (zeros) if ws too small

  unsigned short* x_bf  = (unsigned short*)(ws + OFF_XBF);
  unsigned short* w_bf  = (unsigned short*)(ws + OFF_WBF);
  unsigned short* gx_ws = (unsigned short*)(ws + OFF_GX);
  unsigned int*   h_tag = (unsigned int*)(ws + OFF_HTAG);

  prep_kernel<<<16912, 256, 0, stream>>>(x, w_ih, hx, x_bf, w_bf, h_tag);
  gemm_gx<<<8192, 256, 0, stream>>>(x_bf, w_bf, b_ih, b_hh, gx_ws);
  lstm_rec<<<32, 512, 0, stream>>>(cx, w_hh, gx_ws, h_tag, out);
}

// Round 4
// 8882.746 us; speedup vs baseline: 12.3323x; 1.1012x over previous
//
#include <hip/hip_runtime.h>
#include <stdint.h>

// LSTM forward, B=32 T=2048 D=512 H=512 G=2048.
// Phase 1: prep  — convert x, w_ih to bf16; seed h_tag slot0 (tag 0, sc0sc1);
//                  clear slot1.
// Phase 2: gemm  — gx[t][nw][b][g*16+jl] = x@w_ih^T + (b_ih+b_hh), bf16 in ws.
// Phase 3: rec   — 32 WGs (one per 16 h-cols), w_hh slice in VGPRs,
//                  per-step cross-WG h exchange via tagged dwords
//                  (low16 = bf16 h, high16 = step tag), double-buffered slots.
//                  All loop VMEM is inline asm in a known FIFO order; counted
//                  vmcnt (never 0 in steady state); raw barriers (lgkm only)
//                  so out[] stores stream without ever stalling the chain.

#define B_ 32
#define T_ 2048
#define D_ 512
#define H_ 512
#define G_ 2048
#define NW_ 32

typedef __attribute__((ext_vector_type(4))) float f32x4;
typedef __attribute__((ext_vector_type(8))) short bf16x8;
typedef __attribute__((ext_vector_type(4))) unsigned int uint4v;
typedef __attribute__((ext_vector_type(2))) unsigned int uint2v;

__device__ __forceinline__ unsigned short f2bf(float f) {
  union { float f; unsigned int u; } v; v.f = f;
  unsigned int r = (v.u + 0x7FFFu + ((v.u >> 16) & 1u)) >> 16;
  return (unsigned short)r;
}
__device__ __forceinline__ float bf2f(unsigned short s) {
  union { unsigned int u; float f; } v; v.u = ((unsigned int)s) << 16;
  return v.f;
}
__device__ __forceinline__ float sigm(float x) { return 1.0f / (1.0f + __expf(-x)); }
__device__ __forceinline__ float tanh_(float x) { return 1.0f - 2.0f / (__expf(2.0f * x) + 1.0f); }

__device__ __forceinline__ void store_x4_coherent(unsigned int* p, uint4v v) {
  asm volatile("global_store_dwordx4 %0, %1, off sc0 sc1" :: "v"(p), "v"(v) : "memory");
}

// ---------------- Phase 1: convert inputs + seed/clear h_tag ----------------
__global__ __launch_bounds__(256) void prep_kernel(
    const float* __restrict__ x, const float* __restrict__ w_ih,
    const float* __restrict__ hx,
    unsigned short* __restrict__ x_bf, unsigned short* __restrict__ w_bf,
    unsigned int* __restrict__ h_tag) {
  const int NX8 = (B_ * T_ * D_) / 8;   // 4,194,304
  const int NWT8 = (G_ * D_) / 8;       // 131,072
  int i = blockIdx.x * 256 + threadIdx.x;
  if (i < NX8) {
    float4 a = reinterpret_cast<const float4*>(x)[i * 2];
    float4 b = reinterpret_cast<const float4*>(x)[i * 2 + 1];
    uint4v v;
    v[0] = (unsigned)f2bf(a.x) | ((unsigned)f2bf(a.y) << 16);
    v[1] = (unsigned)f2bf(a.z) | ((unsigned)f2bf(a.w) << 16);
    v[2] = (unsigned)f2bf(b.x) | ((unsigned)f2bf(b.y) << 16);
    v[3] = (unsigned)f2bf(b.z) | ((unsigned)f2bf(b.w) << 16);
    reinterpret_cast<uint4v*>(x_bf)[i] = v;
  } else if (i < NX8 + NWT8) {
    int j = i - NX8;
    float4 a = reinterpret_cast<const float4*>(w_ih)[j * 2];
    float4 b = reinterpret_cast<const float4*>(w_ih)[j * 2 + 1];
    uint4v v;
    v[0] = (unsigned)f2bf(a.x) | ((unsigned)f2bf(a.y) << 16);
    v[1] = (unsigned)f2bf(a.z) | ((unsigned)f2bf(a.w) << 16);
    v[2] = (unsigned)f2bf(b.x) | ((unsigned)f2bf(b.y) << 16);
    v[3] = (unsigned)f2bf(b.z) | ((unsigned)f2bf(b.w) << 16);
    reinterpret_cast<uint4v*>(w_bf)[j] = v;
  } else if (i < NX8 + NWT8 + 2048) {
    int j = i - NX8 - NWT8;  // seed slot 0 from hx, tag 0
    float4 a = reinterpret_cast<const float4*>(hx)[j * 2];
    float4 b = reinterpret_cast<const float4*>(hx)[j * 2 + 1];
    uint4v v0, v1;
    v0[0] = f2bf(a.x); v0[1] = f2bf(a.y); v0[2] = f2bf(a.z); v0[3] = f2bf(a.w);
    v1[0] = f2bf(b.x); v1[1] = f2bf(b.y); v1[2] = f2bf(b.z); v1[3] = f2bf(b.w);
    unsigned int* p = h_tag + j * 8;
    store_x4_coherent(p, v0);
    store_x4_coherent(p + 4, v1);
  } else {
    int j = i - NX8 - NWT8 - 2048;  // clear slot 1
    unsigned int* p = h_tag + 16384 + j * 8;
    uint4v z = {0u, 0u, 0u, 0u};
    store_x4_coherent(p, z);
    store_x4_coherent(p + 4, z);
  }
}

// ---------------- Phase 2: gx GEMM ----------------
__global__ __launch_bounds__(256, 2) void gemm_gx(
    const unsigned short* __restrict__ x_bf, const unsigned short* __restrict__ w_bf,
    const float* __restrict__ b_ih, const float* __restrict__ b_hh,
    unsigned short* __restrict__ gx_ws) {
  __shared__ unsigned short As[128 * 40];
  __shared__ unsigned short Bs[128 * 40];
  __shared__ unsigned short Eg[128 * 136];
  const int bid = blockIdx.x;
  const int cb = bid & 15, rb = bid >> 4;
  const int r0 = rb * 128, c0 = cb * 128;
  const int tid = threadIdx.x;
  const int lane = tid & 63;
  const int w = tid >> 6;
  const int qr = (w >> 1) * 64, qc = (w & 1) * 64;
  f32x4 acc[4][4] = {};

  for (int kt = 0; kt < 16; ++kt) {
    const int k0 = kt * 32;
    uint4v av[2], bv[2];
#pragma unroll
    for (int c = 0; c < 2; ++c) {
      int flat = c * 256 + tid;
      int row = flat >> 2, q = flat & 3;
      av[c] = *reinterpret_cast<const uint4v*>(x_bf + (size_t)(r0 + row) * 512 + k0 + q * 8);
      bv[c] = *reinterpret_cast<const uint4v*>(w_bf + (size_t)(c0 + row) * 512 + k0 + q * 8);
    }
    __syncthreads();
#pragma unroll
    for (int c = 0; c < 2; ++c) {
      int flat = c * 256 + tid;
      int row = flat >> 2, q = flat & 3;
      *reinterpret_cast<uint4v*>(&As[row * 40 + q * 8]) = av[c];
      *reinterpret_cast<uint4v*>(&Bs[row * 40 + q * 8]) = bv[c];
    }
    __syncthreads();
    bf16x8 af[4], bfr[4];
#pragma unroll
    for (int mt = 0; mt < 4; ++mt)
      af[mt] = *reinterpret_cast<const bf16x8*>(&As[(qr + mt * 16 + (lane & 15)) * 40 + (lane >> 4) * 8]);
#pragma unroll
    for (int nt = 0; nt < 4; ++nt)
      bfr[nt] = *reinterpret_cast<const bf16x8*>(&Bs[(qc + nt * 16 + (lane & 15)) * 40 + (lane >> 4) * 8]);
#pragma unroll
    for (int mt = 0; mt < 4; ++mt)
#pragma unroll
      for (int nt = 0; nt < 4; ++nt)
        acc[mt][nt] = __builtin_amdgcn_mfma_f32_16x16x32_bf16(af[mt], bfr[nt], acc[mt][nt], 0, 0, 0);
  }
  __syncthreads();
#pragma unroll
  for (int nt = 0; nt < 4; ++nt) {
    int cg = c0 + qc + nt * 16 + (lane & 15);
    float bias = b_ih[cg] + b_hh[cg];
#pragma unroll
    for (int mt = 0; mt < 4; ++mt)
#pragma unroll
      for (int j = 0; j < 4; ++j) {
        int tr = qr + mt * 16 + (lane >> 4) * 4 + j;
        int cl = qc + nt * 16 + (lane & 15);
        Eg[tr * 136 + cl] = f2bf(acc[mt][nt][j] + bias);
      }
  }
  __syncthreads();
  const int b = r0 >> 11;
  const int g = c0 >> 9;
  const int t0 = r0 & 2047;
  const int nw0 = (c0 & 511) >> 4;
  for (int c = tid; c < 1024; c += 256) {
    int tr = c >> 3, nwi = c & 7;
    size_t dst = ((size_t)(t0 + tr) * NW_ + (nw0 + nwi)) * 2048 + b * 64 + g * 16;
    uint4v v0 = *reinterpret_cast<const uint4v*>(&Eg[tr * 136 + nwi * 16]);
    uint4v v1 = *reinterpret_cast<const uint4v*>(&Eg[tr * 136 + nwi * 16 + 8]);
    *reinterpret_cast<uint4v*>(gx_ws + dst) = v0;
    *reinterpret_cast<uint4v*>(gx_ws + dst + 8) = v1;
  }
}

// ---------------- Phase 3: recurrence ----------------
#define PLOADS(SL)                                                                             \
  do {                                                                                         \
    const unsigned int* hpA_ = (SL) + pollOff;                                                 \
    const unsigned int* hpB_ = hpA_ + 1024;                                                    \
    asm volatile("global_load_dwordx4 %0, %1, off sc0 sc1" : "=v"(hv[0]) : "v"(hpA_));         \
    asm volatile("global_load_dwordx4 %0, %1, off offset:1024 sc0 sc1" : "=v"(hv[1]) : "v"(hpA_)); \
    asm volatile("global_load_dwordx4 %0, %1, off offset:2048 sc0 sc1" : "=v"(hv[2]) : "v"(hpA_)); \
    asm volatile("global_load_dwordx4 %0, %1, off offset:3072 sc0 sc1" : "=v"(hv[3]) : "v"(hpA_)); \
    asm volatile("global_load_dwordx4 %0, %1, off sc0 sc1" : "=v"(hv[4]) : "v"(hpB_));         \
    asm volatile("global_load_dwordx4 %0, %1, off offset:1024 sc0 sc1" : "=v"(hv[5]) : "v"(hpB_)); \
    asm volatile("global_load_dwordx4 %0, %1, off offset:2048 sc0 sc1" : "=v"(hv[6]) : "v"(hpB_)); \
    asm volatile("global_load_dwordx4 %0, %1, off offset:3072 sc0 sc1" : "=v"(hv[7]) : "v"(hpB_)); \
  } while (0)

#define CHECKBAD(WANT, BAD)                                     \
  do {                                                          \
    BAD = 0u;                                                   \
    _Pragma("unroll") for (int i_ = 0; i_ < 8; ++i_)            \
      _Pragma("unroll") for (int k_ = 0; k_ < 4; ++k_)          \
        BAD |= (hv[i_][k_] >> 16) ^ (WANT);                     \
  } while (0)

#define UNPACK_AS()                                                       \
  do {                                                                    \
    _Pragma("unroll") for (int i_ = 0; i_ < 8; ++i_) {                    \
      int row_ = (w << 2) | (i_ >> 1);                                    \
      int col_ = ((i_ & 1) << 8) | (lane << 2);                           \
      uint2v p_;                                                          \
      p_[0] = (hv[i_][0] & 0xffffu) | (hv[i_][1] << 16);                  \
      p_[1] = (hv[i_][2] & 0xffffu) | (hv[i_][3] << 16);                  \
      *reinterpret_cast<uint2v*>(&As[row_ * 520 + col_]) = p_;            \
    }                                                                     \
  } while (0)

#define BARRIER_LGKM()                                          \
  do {                                                          \
    asm volatile("s_waitcnt lgkmcnt(0)" ::: "memory");          \
    __builtin_amdgcn_sched_barrier(0);                          \
    __builtin_amdgcn_s_barrier();                               \
    __builtin_amdgcn_sched_barrier(0);                          \
  } while (0)

__global__ __launch_bounds__(512, 2) void lstm_rec(
    const float* __restrict__ cx, const float* __restrict__ w_hh,
    const unsigned short* __restrict__ gx_ws, unsigned int* __restrict__ h_tag,
    float* __restrict__ out) {
  const int bid = blockIdx.x;
  const int nw = ((bid & 7) << 2) | (bid >> 3);  // pair adjacent nw on one XCD
  const int tid = threadIdx.x;
  const int lane = tid & 63;
  const int w = tid >> 6;
  const int mt = w >> 2;
  const int g = w & 3;
  __shared__ unsigned short As[32 * 520];   // h tile (bf16), pad 512->520
  __shared__ float Gt[32 * 68];             // MFMA gate sums, pad 64->68
  __shared__ unsigned short Gx[2][32 * 72]; // gx chunk dbuf, pad 64->72

  // w_hh slice -> registers (16 bf16x8 frags = 64 VGPR)
  bf16x8 breg[16];
  {
    const int gcol = g * 512 + nw * 16 + (lane & 15);
    const float* wrow = w_hh + (size_t)gcol * 512;
#pragma unroll
    for (int kk = 0; kk < 16; ++kk) {
      int k = kk * 32 + (lane >> 4) * 8;
      float4 f0 = *reinterpret_cast<const float4*>(wrow + k);
      float4 f1 = *reinterpret_cast<const float4*>(wrow + k + 4);
      uint4v v;
      v[0] = (unsigned)f2bf(f0.x) | ((unsigned)f2bf(f0.y) << 16);
      v[1] = (unsigned)f2bf(f0.z) | ((unsigned)f2bf(f0.w) << 16);
      v[2] = (unsigned)f2bf(f1.x) | ((unsigned)f2bf(f1.y) << 16);
      v[3] = (unsigned)f2bf(f1.z) | ((unsigned)f2bf(f1.w) << 16);
      breg[kk] = __builtin_bit_cast(bf16x8, v);
    }
  }
  const int eb = tid >> 4;
  const int jl = tid & 15;
  const int jh = nw * 16 + jl;
  float c = cx[eb * 512 + jh];

  float* outF = out + (size_t)eb * (T_ * H_) + jh;
  float* outH = outF + (size_t)B_ * T_ * H_;
  float* outG = outH + (size_t)B_ * T_ * H_;

  unsigned int* slot0 = h_tag;
  unsigned int* slot1 = h_tag + 16384;
  // wave-coalesced poll: instr i of wave w covers dwords w*2048+i*256+lane*4
  const int pollOff = (w << 11) | (lane << 2);

  const unsigned short* gx_base = gx_ws + (size_t)nw * 2048;
  uint4v hv[8];

  // ---- prologue: fill Gx[0] and As for t=0 (tags seeded = 0)
  {
    uint2v g2 = *reinterpret_cast<const uint2v*>(gx_base + tid * 4);
    *reinterpret_cast<uint2v*>(&Gx[0][(tid >> 4) * 72 + (tid & 15) * 4]) = g2;
    PLOADS(slot0);
    asm volatile("s_waitcnt vmcnt(0)" ::: "memory");
    __builtin_amdgcn_sched_barrier(0);
    unsigned bad;
    CHECKBAD(0u, bad);
    int guard = 0;
    while (bad) {
      PLOADS(slot0);
      asm volatile("s_waitcnt vmcnt(0)" ::: "memory");
      __builtin_amdgcn_sched_barrier(0);
      CHECKBAD(0u, bad);
      if (++guard > (1 << 20)) break;
    }
    UNPACK_AS();
  }

  for (int t = 0; t < T_; ++t) {
    BARRIER_LGKM();  // A: As + Gx[t&1] ready for all
    // ---- MFMA: two independent 8-chains over K=512
    f32x4 a0 = {}, a1 = {};
#pragma unroll
    for (int kk = 0; kk < 8; ++kk) {
      bf16x8 af = *reinterpret_cast<const bf16x8*>(
          &As[(mt * 16 + (lane & 15)) * 520 + kk * 32 + (lane >> 4) * 8]);
      a0 = __builtin_amdgcn_mfma_f32_16x16x32_bf16(af, breg[kk], a0, 0, 0, 0);
    }
#pragma unroll
    for (int kk = 8; kk < 16; ++kk) {
      bf16x8 af = *reinterpret_cast<const bf16x8*>(
          &As[(mt * 16 + (lane & 15)) * 520 + kk * 32 + (lane >> 4) * 8]);
      a1 = __builtin_amdgcn_mfma_f32_16x16x32_bf16(af, breg[kk], a1, 0, 0, 0);
    }
#pragma unroll
    for (int j = 0; j < 4; ++j)
      Gt[(mt * 16 + (lane >> 4) * 4 + j) * 68 + g * 16 + (lane & 15)] = a0[j] + a1[j];
    BARRIER_LGKM();  // B: Gt ready
    // ---- elementwise
    const int gxb = t & 1;
    float iv = Gt[eb * 68 + jl]      + bf2f(Gx[gxb][eb * 72 + jl]);
    float fv = Gt[eb * 68 + 16 + jl] + bf2f(Gx[gxb][eb * 72 + 16 + jl]);
    float gv = Gt[eb * 68 + 32 + jl] + bf2f(Gx[gxb][eb * 72 + 32 + jl]);
    float ov = Gt[eb * 68 + 48 + jl] + bf2f(Gx[gxb][eb * 72 + 48 + jl]);
    float ia = sigm(iv), fa = sigm(fv), ga = tanh_(gv), oa = sigm(ov);
    c = fa * c + ia * ga;
    float h = oa * tanh_(c);
    unsigned int* nslot = (t & 1) ? slot0 : slot1;  // slot (t+1)&1
    // 1) publish (packed pairs, sc0sc1)
    {
      unsigned int word = (unsigned int)f2bf(h) | (((unsigned int)(t + 1)) << 16);
      unsigned int pw = __shfl_xor(word, 1);
      if (!(tid & 1)) {
        unsigned long long dw = ((unsigned long long)pw << 32) | (unsigned long long)word;
        unsigned int* pp = nslot + eb * 512 + jh;
        asm volatile("global_store_dwordx2 %0, %1, off sc0 sc1" :: "v"(pp), "v"(dw) : "memory");
      }
    }
    // 2) issue next-step polls + gx prefetch (overlap publish visibility)
    uint2v gx2;
    if (t + 1 < T_) {
      PLOADS(nslot);
      const unsigned short* gp = gx_base + (size_t)(t + 1) * 65536 + tid * 4;
      asm volatile("global_load_dwordx2 %0, %1, off" : "=v"(gx2) : "v"(gp));
    }
    // 3) out stores — streamed, never waited on in-loop
    {
      const float* pf = outF + (size_t)t * H_;
      const float* ph = outH + (size_t)t * H_;
      const float* pg = outG + (size_t)t * H_;
      asm volatile("global_store_dword %0, %1, off" :: "v"(pf), "v"(fa) : "memory");
      asm volatile("global_store_dword %0, %1, off" :: "v"(ph), "v"(h) : "memory");
      asm volatile("global_store_dword %0, %1, off" :: "v"(pg), "v"(ga) : "memory");
    }
    if (t + 1 >= T_) {
      out[(size_t)3 * B_ * T_ * H_ + eb * H_ + jh] = oa;  // outgate_last
      break;
    }
    // ---- check polls: FIFO = [pub][p0..7][gx2][out*3] -> vmcnt(4) covers polls
    asm volatile("s_waitcnt vmcnt(4)" ::: "memory");
    __builtin_amdgcn_sched_barrier(0);
    const unsigned want = (unsigned)(t + 1);
    unsigned bad;
    CHECKBAD(want, bad);
    int guard = 0;
    while (bad) {
      PLOADS(nslot);
      asm volatile("s_waitcnt vmcnt(0)" ::: "memory");
      __builtin_amdgcn_sched_barrier(0);
      CHECKBAD(want, bad);
      if (++guard > (1 << 20)) break;
    }
    UNPACK_AS();
    asm volatile("s_waitcnt vmcnt(3)" ::: "memory");  // gx2 retired
    __builtin_amdgcn_sched_barrier(0);
    *reinterpret_cast<uint2v*>(&Gx[(t + 1) & 1][(tid >> 4) * 72 + (tid & 15) * 4]) = gx2;
  }
}

extern "C" void kernel_launch(void* const* d_in, const int* in_sizes, int n_in,
                              void* d_out, int out_size, void* d_ws, size_t ws_size,
                              hipStream_t stream) {
  const float* x    = (const float*)d_in[0];
  const float* hx   = (const float*)d_in[1];
  const float* cx   = (const float*)d_in[2];
  const float* w_ih = (const float*)d_in[3];
  const float* w_hh = (const float*)d_in[4];
  const float* b_ih = (const float*)d_in[5];
  const float* b_hh = (const float*)d_in[6];
  float* out = (float*)d_out;
  char* ws = (char*)d_ws;
  const size_t OFF_XBF  = 0;                    // 67,108,864
  const size_t OFF_WBF  = 67108864;             //  2,097,152
  const size_t OFF_GX   = 69206016;             // 268,435,456
  const size_t OFF_HTAG = 337641472;            //    131,072
  const size_t NEEDED   = 337772544;
  if (ws_size < NEEDED) return;

  unsigned short* x_bf  = (unsigned short*)(ws + OFF_XBF);
  unsigned short* w_bf  = (unsigned short*)(ws + OFF_WBF);
  unsigned short* gx_ws = (unsigned short*)(ws + OFF_GX);
  unsigned int*   h_tag = (unsigned int*)(ws + OFF_HTAG);

  prep_kernel<<<16912, 256, 0, stream>>>(x, w_ih, hx, x_bf, w_bf, h_tag);
  gemm_gx<<<8192, 256, 0, stream>>>(x_bf, w_bf, b_ih, b_hh, gx_ws);
  lstm_rec<<<32, 512, 0, stream>>>(cx, w_hh, gx_ws, h_tag, out);
}

// Round 5
// 5609.739 us; speedup vs baseline: 19.5277x; 1.5835x over previous
//
#include <hip/hip_runtime.h>
#include <stdint.h>

// LSTM forward, B=32 T=2048 D=512 H=512 G=2048.
// Phase 3 rethink: batch chains are INDEPENDENT -> split consumers by batch.
// 128 WGs = 16 col-groups (nw: 32 h-cols) x 8 batch-groups (bg: 4 batches).
// Per step each WG polls only its 4 batch rows of tagged h (8KB, sc0sc1),
// computes gates[4 x 128] via MFMA (M=16, rows 4x-duplicated), publishes
// 128 tagged dwords. Tag+payload share a dword => no fences.

#define B_ 32
#define T_ 2048
#define D_ 512
#define H_ 512
#define G_ 2048
#define NCG 16
#define NBG 8

typedef __attribute__((ext_vector_type(4))) float f32x4;
typedef __attribute__((ext_vector_type(8))) short bf16x8;
typedef __attribute__((ext_vector_type(4))) unsigned int uint4v;
typedef __attribute__((ext_vector_type(2))) unsigned int uint2v;

__device__ __forceinline__ unsigned short f2bf(float f) {
  union { float f; unsigned int u; } v; v.f = f;
  unsigned int r = (v.u + 0x7FFFu + ((v.u >> 16) & 1u)) >> 16;
  return (unsigned short)r;
}
__device__ __forceinline__ float bf2f(unsigned short s) {
  union { unsigned int u; float f; } v; v.u = ((unsigned int)s) << 16;
  return v.f;
}
__device__ __forceinline__ float sigm(float x) { return 1.0f / (1.0f + __expf(-x)); }
__device__ __forceinline__ float tanh_(float x) { return 1.0f - 2.0f / (__expf(2.0f * x) + 1.0f); }

__device__ __forceinline__ void store_x4_coherent(unsigned int* p, uint4v v) {
  asm volatile("global_store_dwordx4 %0, %1, off sc0 sc1" :: "v"(p), "v"(v) : "memory");
}

#define BARRIER_LGKM()                                          \
  do {                                                          \
    asm volatile("s_waitcnt lgkmcnt(0)" ::: "memory");          \
    __builtin_amdgcn_sched_barrier(0);                          \
    __builtin_amdgcn_s_barrier();                               \
    __builtin_amdgcn_sched_barrier(0);                          \
  } while (0)

// ---------------- Phase 1: convert inputs + seed/clear h_tag ----------------
__global__ __launch_bounds__(256) void prep_kernel(
    const float* __restrict__ x, const float* __restrict__ w_ih,
    const float* __restrict__ hx,
    unsigned short* __restrict__ x_bf, unsigned short* __restrict__ w_bf,
    unsigned int* __restrict__ h_tag) {
  const int NX8 = (B_ * T_ * D_) / 8;   // 4,194,304
  const int NWT8 = (G_ * D_) / 8;       // 131,072
  int i = blockIdx.x * 256 + threadIdx.x;
  if (i < NX8) {
    float4 a = reinterpret_cast<const float4*>(x)[i * 2];
    float4 b = reinterpret_cast<const float4*>(x)[i * 2 + 1];
    uint4v v;
    v[0] = (unsigned)f2bf(a.x) | ((unsigned)f2bf(a.y) << 16);
    v[1] = (unsigned)f2bf(a.z) | ((unsigned)f2bf(a.w) << 16);
    v[2] = (unsigned)f2bf(b.x) | ((unsigned)f2bf(b.y) << 16);
    v[3] = (unsigned)f2bf(b.z) | ((unsigned)f2bf(b.w) << 16);
    reinterpret_cast<uint4v*>(x_bf)[i] = v;
  } else if (i < NX8 + NWT8) {
    int j = i - NX8;
    float4 a = reinterpret_cast<const float4*>(w_ih)[j * 2];
    float4 b = reinterpret_cast<const float4*>(w_ih)[j * 2 + 1];
    uint4v v;
    v[0] = (unsigned)f2bf(a.x) | ((unsigned)f2bf(a.y) << 16);
    v[1] = (unsigned)f2bf(a.z) | ((unsigned)f2bf(a.w) << 16);
    v[2] = (unsigned)f2bf(b.x) | ((unsigned)f2bf(b.y) << 16);
    v[3] = (unsigned)f2bf(b.z) | ((unsigned)f2bf(b.w) << 16);
    reinterpret_cast<uint4v*>(w_bf)[j] = v;
  } else if (i < NX8 + NWT8 + 2048) {
    int j = i - NX8 - NWT8;  // seed slot 0 from hx, tag 0
    float4 a = reinterpret_cast<const float4*>(hx)[j * 2];
    float4 b = reinterpret_cast<const float4*>(hx)[j * 2 + 1];
    uint4v v0, v1;
    v0[0] = f2bf(a.x); v0[1] = f2bf(a.y); v0[2] = f2bf(a.z); v0[3] = f2bf(a.w);
    v1[0] = f2bf(b.x); v1[1] = f2bf(b.y); v1[2] = f2bf(b.z); v1[3] = f2bf(b.w);
    unsigned int* p = h_tag + j * 8;
    store_x4_coherent(p, v0);
    store_x4_coherent(p + 4, v1);
  } else {
    int j = i - NX8 - NWT8 - 2048;  // clear slot 1
    unsigned int* p = h_tag + 16384 + j * 8;
    uint4v z = {0u, 0u, 0u, 0u};
    store_x4_coherent(p, z);
    store_x4_coherent(p + 4, z);
  }
}

// ---------------- Phase 2: gx GEMM ----------------
// 128x128 tile over rows r=b*2048+t, cols gcol. Epilogue writes
// gx[t][bg][nw][bq(4)][g(4)][jl(32)] bf16 (64B runs).
__global__ __launch_bounds__(256, 2) void gemm_gx(
    const unsigned short* __restrict__ x_bf, const unsigned short* __restrict__ w_bf,
    const float* __restrict__ b_ih, const float* __restrict__ b_hh,
    unsigned short* __restrict__ gx_ws) {
  __shared__ unsigned short As[128 * 40];
  __shared__ unsigned short Bs[128 * 40];
  __shared__ unsigned short Eg[128 * 136];
  const int bid = blockIdx.x;
  const int cb = bid & 15, rb = bid >> 4;
  const int r0 = rb * 128, c0 = cb * 128;
  const int tid = threadIdx.x;
  const int lane = tid & 63;
  const int w = tid >> 6;
  const int qr = (w >> 1) * 64, qc = (w & 1) * 64;
  f32x4 acc[4][4] = {};

  for (int kt = 0; kt < 16; ++kt) {
    const int k0 = kt * 32;
    uint4v av[2], bv[2];
#pragma unroll
    for (int c = 0; c < 2; ++c) {
      int flat = c * 256 + tid;
      int row = flat >> 2, q = flat & 3;
      av[c] = *reinterpret_cast<const uint4v*>(x_bf + (size_t)(r0 + row) * 512 + k0 + q * 8);
      bv[c] = *reinterpret_cast<const uint4v*>(w_bf + (size_t)(c0 + row) * 512 + k0 + q * 8);
    }
    __syncthreads();
#pragma unroll
    for (int c = 0; c < 2; ++c) {
      int flat = c * 256 + tid;
      int row = flat >> 2, q = flat & 3;
      *reinterpret_cast<uint4v*>(&As[row * 40 + q * 8]) = av[c];
      *reinterpret_cast<uint4v*>(&Bs[row * 40 + q * 8]) = bv[c];
    }
    __syncthreads();
    bf16x8 af[4], bfr[4];
#pragma unroll
    for (int mt = 0; mt < 4; ++mt)
      af[mt] = *reinterpret_cast<const bf16x8*>(&As[(qr + mt * 16 + (lane & 15)) * 40 + (lane >> 4) * 8]);
#pragma unroll
    for (int nt = 0; nt < 4; ++nt)
      bfr[nt] = *reinterpret_cast<const bf16x8*>(&Bs[(qc + nt * 16 + (lane & 15)) * 40 + (lane >> 4) * 8]);
#pragma unroll
    for (int mt = 0; mt < 4; ++mt)
#pragma unroll
      for (int nt = 0; nt < 4; ++nt)
        acc[mt][nt] = __builtin_amdgcn_mfma_f32_16x16x32_bf16(af[mt], bfr[nt], acc[mt][nt], 0, 0, 0);
  }
  __syncthreads();
#pragma unroll
  for (int nt = 0; nt < 4; ++nt) {
    int cg = c0 + qc + nt * 16 + (lane & 15);
    float bias = b_ih[cg] + b_hh[cg];
#pragma unroll
    for (int mt = 0; mt < 4; ++mt)
#pragma unroll
      for (int j = 0; j < 4; ++j) {
        int tr = qr + mt * 16 + (lane >> 4) * 4 + j;
        int cl = qc + nt * 16 + (lane & 15);
        Eg[tr * 136 + cl] = f2bf(acc[mt][nt][j] + bias);
      }
  }
  __syncthreads();
  const int b = r0 >> 11;          // batch, constant per tile
  const int g = c0 >> 9;           // gate, constant per tile
  const int t0 = r0 & 2047;
  const int nw0 = (c0 & 511) >> 5; // 4 col-groups per tile
  const int bg = b >> 2, bq = b & 3;
  for (int c = tid; c < 512; c += 256) {
    int tr = c >> 2, nwi = c & 3;
    size_t dst = (((size_t)(t0 + tr) * NBG + bg) * NCG + (nw0 + nwi)) * 512 + bq * 128 + g * 32;
    const unsigned short* src = &Eg[tr * 136 + nwi * 32];
#pragma unroll
    for (int q = 0; q < 4; ++q)
      *reinterpret_cast<uint4v*>(gx_ws + dst + q * 8) =
          *reinterpret_cast<const uint4v*>(src + q * 8);
  }
}

// ---------------- Phase 3: recurrence ----------------
// 128 WGs x 512 threads. WG (nw=bid&15, bg=bid>>4): h-cols [nw*32,+32),
// batches [bg*4,+4). Wave w = K-slice kh (64 cols). Slot: [s][b(32)][512] dw.
__global__ __launch_bounds__(512) void lstm_rec(
    const float* __restrict__ cx, const float* __restrict__ w_hh,
    const unsigned short* __restrict__ gx_ws, unsigned int* __restrict__ h_tag,
    float* __restrict__ out) {
  const int bid = blockIdx.x;
  const int nw = bid & 15;
  const int bg = bid >> 4;
  const int tid = threadIdx.x;
  const int lane = tid & 63;
  const int w = tid >> 6;  // kh
  __shared__ unsigned short As[4 * 536];      // h rows (bf16), stride 536
  __shared__ float Gt[8 * 8 * 16 * 4];        // [kh][tile n][cl 16][bq 4]
  __shared__ unsigned short GxL[2][512];      // gx dbuf [bq][g][jl]

  // B-frags: 8 N-tiles (gi*2+half) x 2 k-steps, 64 VGPR
  bf16x8 breg[8][2];
#pragma unroll
  for (int n = 0; n < 8; ++n) {
    int gi = n >> 1, half = n & 1;
    int gcol = gi * 512 + nw * 32 + half * 16 + (lane & 15);
    const float* wrow = w_hh + (size_t)gcol * 512;
#pragma unroll
    for (int ss = 0; ss < 2; ++ss) {
      int k = w * 64 + ss * 32 + (lane >> 4) * 8;
      float4 f0 = *reinterpret_cast<const float4*>(wrow + k);
      float4 f1 = *reinterpret_cast<const float4*>(wrow + k + 4);
      uint4v v;
      v[0] = (unsigned)f2bf(f0.x) | ((unsigned)f2bf(f0.y) << 16);
      v[1] = (unsigned)f2bf(f0.z) | ((unsigned)f2bf(f0.w) << 16);
      v[2] = (unsigned)f2bf(f1.x) | ((unsigned)f2bf(f1.y) << 16);
      v[3] = (unsigned)f2bf(f1.z) | ((unsigned)f2bf(f1.w) << 16);
      breg[n][ss] = __builtin_bit_cast(bf16x8, v);
    }
  }
  // elementwise ownership (waves 0,1): lane -> (bq=lane&3, cl=lane>>2),
  // jl = w*16+cl, col = nw*32+jl, batch = bg*4+bq
  const int bq = lane & 3;
  const int cl = lane >> 2;
  const int jl = (w & 1) * 16 + cl;
  const int col = nw * 32 + jl;
  const int bno = bg * 4 + bq;
  float c = 0.0f;
  if (w < 2) c = cx[bno * 512 + col];

  unsigned int* slot0 = h_tag;
  unsigned int* slot1 = h_tag + 16384;
  const unsigned int* pollp0 = slot0 + bg * 2048 + tid * 4;
  const unsigned int* pollp1 = slot1 + bg * 2048 + tid * 4;
  const unsigned short* gx_base = gx_ws + ((size_t)bg * NCG + nw) * 512;
  const size_t gx_tstride = (size_t)NBG * NCG * 512;

  uint4v hv;
  uint4v gxr;

  // ---- prologue: gx[0] + poll t=0 (tags seeded 0)
  if (w == 0)
    asm volatile("global_load_dwordx4 %0, %1, off"
                 : "=v"(gxr) : "v"(gx_base + lane * 8));
  {
    asm volatile("global_load_dwordx4 %0, %1, off sc0 sc1" : "=v"(hv) : "v"(pollp0));
    int guard = 0;
    for (;;) {
      asm volatile("s_waitcnt vmcnt(0)" ::: "memory");
      __builtin_amdgcn_sched_barrier(0);
      unsigned bad = (hv[0] >> 16) | (hv[1] >> 16) | (hv[2] >> 16) | (hv[3] >> 16);
      if (!bad || ++guard > (1 << 20)) break;
      asm volatile("global_load_dwordx4 %0, %1, off sc0 sc1" : "=v"(hv) : "v"(pollp0));
    }
    uint2v pk;
    pk[0] = (hv[0] & 0xffffu) | (hv[1] << 16);
    pk[1] = (hv[2] & 0xffffu) | (hv[3] << 16);
    *reinterpret_cast<uint2v*>(&As[(tid >> 7) * 536 + (tid & 127) * 4]) = pk;
  }
  if (w == 0)
    *reinterpret_cast<uint4v*>(&GxL[0][lane * 8]) = __builtin_bit_cast(uint4v, gxr);

  for (int t = 0; t < T_; ++t) {
    BARRIER_LGKM();  // A: As + GxL[t&1] ready
    const bool more = (t + 1 < T_);
    if (w == 0 && more)
      asm volatile("global_load_dwordx4 %0, %1, off"
                   : "=v"(gxr) : "v"(gx_base + (size_t)(t + 1) * gx_tstride + lane * 8));
    // ---- MFMA: A-frag shared across 8 N-tiles; rows 4x-duplicated
    bf16x8 af0 = *reinterpret_cast<const bf16x8*>(
        &As[(lane & 3) * 536 + w * 64 + (lane >> 4) * 8]);
    bf16x8 af1 = *reinterpret_cast<const bf16x8*>(
        &As[(lane & 3) * 536 + w * 64 + 32 + (lane >> 4) * 8]);
    f32x4 acc[8] = {};
#pragma unroll
    for (int n = 0; n < 8; ++n)
      acc[n] = __builtin_amdgcn_mfma_f32_16x16x32_bf16(af0, breg[n][0], acc[n], 0, 0, 0);
#pragma unroll
    for (int n = 0; n < 8; ++n)
      acc[n] = __builtin_amdgcn_mfma_f32_16x16x32_bf16(af1, breg[n][1], acc[n], 0, 0, 0);
    if (lane < 16) {
#pragma unroll
      for (int n = 0; n < 8; ++n)
        *reinterpret_cast<f32x4*>(&Gt[((w * 8 + n) * 16 + lane) * 4]) = acc[n];
    }
    BARRIER_LGKM();  // B: Gt complete
    const unsigned int* pollp = (t & 1) ? pollp0 : pollp1;
    if (w >= 2) {
      if (more)
        asm volatile("global_load_dwordx4 %0, %1, off sc0 sc1" : "=v"(hv) : "v"(pollp));
    } else {
      // ---- elementwise (waves 0,1): 128 outputs
      const int gxb = t & 1;
      float s[4];
#pragma unroll
      for (int gi = 0; gi < 4; ++gi) {
        float a = 0.0f;
#pragma unroll
        for (int kh = 0; kh < 8; ++kh)
          a += Gt[(kh * 8 + gi * 2 + (w & 1)) * 64 + lane];
        s[gi] = a + bf2f(GxL[gxb][bq * 128 + gi * 32 + jl]);
      }
      float ia = sigm(s[0]), fa = sigm(s[1]), ga = tanh_(s[2]), oa = sigm(s[3]);
      c = fa * c + ia * ga;
      float h = oa * tanh_(c);
      if (more) {  // publish first (critical path)
        unsigned int word = (unsigned int)f2bf(h) | (((unsigned int)(t + 1)) << 16);
        unsigned int* pp = ((t & 1) ? slot0 : slot1) + bno * 512 + col;
        asm volatile("global_store_dword %0, %1, off sc0 sc1" :: "v"(pp), "v"(word) : "memory");
      }
      size_t bo = (size_t)bno * (T_ * H_) + (size_t)t * H_ + col;
      out[bo] = fa;
      out[(size_t)B_ * T_ * H_ + bo] = h;
      out[(size_t)2 * B_ * T_ * H_ + bo] = ga;
      if (!more) out[(size_t)3 * B_ * T_ * H_ + bno * 512 + col] = oa;
      if (more)
        asm volatile("global_load_dwordx4 %0, %1, off sc0 sc1" : "=v"(hv) : "v"(pollp));
    }
    if (more) {
      const unsigned want = (unsigned)(t + 1);
      int guard = 0;
      for (;;) {
        asm volatile("s_waitcnt vmcnt(0)" ::: "memory");
        __builtin_amdgcn_sched_barrier(0);
        unsigned bad = ((hv[0] >> 16) ^ want) | ((hv[1] >> 16) ^ want) |
                       ((hv[2] >> 16) ^ want) | ((hv[3] >> 16) ^ want);
        if (!bad || ++guard > (1 << 20)) break;
        asm volatile("global_load_dwordx4 %0, %1, off sc0 sc1" : "=v"(hv) : "v"(pollp));
      }
      uint2v pk;
      pk[0] = (hv[0] & 0xffffu) | (hv[1] << 16);
      pk[1] = (hv[2] & 0xffffu) | (hv[3] << 16);
      *reinterpret_cast<uint2v*>(&As[(tid >> 7) * 536 + (tid & 127) * 4]) = pk;
      if (w == 0)
        *reinterpret_cast<uint4v*>(&GxL[(t + 1) & 1][lane * 8]) = __builtin_bit_cast(uint4v, gxr);
    }
  }
}

extern "C" void kernel_launch(void* const* d_in, const int* in_sizes, int n_in,
                              void* d_out, int out_size, void* d_ws, size_t ws_size,
                              hipStream_t stream) {
  const float* x    = (const float*)d_in[0];
  const float* hx   = (const float*)d_in[1];
  const float* cx   = (const float*)d_in[2];
  const float* w_ih = (const float*)d_in[3];
  const float* w_hh = (const float*)d_in[4];
  const float* b_ih = (const float*)d_in[5];
  const float* b_hh = (const float*)d_in[6];
  float* out = (float*)d_out;
  char* ws = (char*)d_ws;
  const size_t OFF_XBF  = 0;                    // 67,108,864
  const size_t OFF_WBF  = 67108864;             //  2,097,152
  const size_t OFF_GX   = 69206016;             // 268,435,456
  const size_t OFF_HTAG = 337641472;            //    131,072
  const size_t NEEDED   = 337772544;
  if (ws_size < NEEDED) return;

  unsigned short* x_bf  = (unsigned short*)(ws + OFF_XBF);
  unsigned short* w_bf  = (unsigned short*)(ws + OFF_WBF);
  unsigned short* gx_ws = (unsigned short*)(ws + OFF_GX);
  unsigned int*   h_tag = (unsigned int*)(ws + OFF_HTAG);

  prep_kernel<<<16912, 256, 0, stream>>>(x, w_ih, hx, x_bf, w_bf, h_tag);
  gemm_gx<<<8192, 256, 0, stream>>>(x_bf, w_bf, b_ih, b_hh, gx_ws);
  lstm_rec<<<128, 512, 0, stream>>>(cx, w_hh, gx_ws, h_tag, out);
}

// Round 6
// 5409.348 us; speedup vs baseline: 20.2511x; 1.0370x over previous
//
#include <hip/hip_runtime.h>
#include <stdint.h>

// LSTM forward, B=32 T=2048 D=512 H=512 G=2048.
// Round 6: (1) XCD-local exchange fast path — bg = bid&7 puts each sync
// domain (16 WGs sharing a batch-group) on one XCD (round-robin dispatch
// assumption); polls try sc0-only (local L2) first, fall back to sc0sc1
// (MALL, always correct). Entry fence(ACQUIRE,agent) invalidates stale
// L1/L2 lines from previous graph replays (tags repeat across replays!).
// (2) Full-K-per-wave MFMA: wave n owns one 16-col N-tile with K=512,
// killing the 8-way cross-wave reduction (32 LDS reads -> 4).

#define B_ 32
#define T_ 2048
#define D_ 512
#define H_ 512
#define G_ 2048
#define NCG 16
#define NBG 8

typedef __attribute__((ext_vector_type(4))) float f32x4;
typedef __attribute__((ext_vector_type(8))) short bf16x8;
typedef __attribute__((ext_vector_type(4))) unsigned int uint4v;
typedef __attribute__((ext_vector_type(2))) unsigned int uint2v;

__device__ __forceinline__ unsigned short f2bf(float f) {
  union { float f; unsigned int u; } v; v.f = f;
  unsigned int r = (v.u + 0x7FFFu + ((v.u >> 16) & 1u)) >> 16;
  return (unsigned short)r;
}
__device__ __forceinline__ float bf2f(unsigned short s) {
  union { unsigned int u; float f; } v; v.u = ((unsigned int)s) << 16;
  return v.f;
}
__device__ __forceinline__ float sigm(float x) { return 1.0f / (1.0f + __expf(-x)); }
__device__ __forceinline__ float tanh_(float x) { return 1.0f - 2.0f / (__expf(2.0f * x) + 1.0f); }

__device__ __forceinline__ void store_x4_coherent(unsigned int* p, uint4v v) {
  asm volatile("global_store_dwordx4 %0, %1, off sc0 sc1" :: "v"(p), "v"(v) : "memory");
}

#define BARRIER_LGKM()                                          \
  do {                                                          \
    asm volatile("s_waitcnt lgkmcnt(0)" ::: "memory");          \
    __builtin_amdgcn_sched_barrier(0);                          \
    __builtin_amdgcn_s_barrier();                               \
    __builtin_amdgcn_sched_barrier(0);                          \
  } while (0)

// ---------------- Phase 1: convert inputs + seed/clear h_tag ----------------
__global__ __launch_bounds__(256) void prep_kernel(
    const float* __restrict__ x, const float* __restrict__ w_ih,
    const float* __restrict__ hx,
    unsigned short* __restrict__ x_bf, unsigned short* __restrict__ w_bf,
    unsigned int* __restrict__ h_tag) {
  const int NX8 = (B_ * T_ * D_) / 8;   // 4,194,304
  const int NWT8 = (G_ * D_) / 8;       // 131,072
  int i = blockIdx.x * 256 + threadIdx.x;
  if (i < NX8) {
    float4 a = reinterpret_cast<const float4*>(x)[i * 2];
    float4 b = reinterpret_cast<const float4*>(x)[i * 2 + 1];
    uint4v v;
    v[0] = (unsigned)f2bf(a.x) | ((unsigned)f2bf(a.y) << 16);
    v[1] = (unsigned)f2bf(a.z) | ((unsigned)f2bf(a.w) << 16);
    v[2] = (unsigned)f2bf(b.x) | ((unsigned)f2bf(b.y) << 16);
    v[3] = (unsigned)f2bf(b.z) | ((unsigned)f2bf(b.w) << 16);
    reinterpret_cast<uint4v*>(x_bf)[i] = v;
  } else if (i < NX8 + NWT8) {
    int j = i - NX8;
    float4 a = reinterpret_cast<const float4*>(w_ih)[j * 2];
    float4 b = reinterpret_cast<const float4*>(w_ih)[j * 2 + 1];
    uint4v v;
    v[0] = (unsigned)f2bf(a.x) | ((unsigned)f2bf(a.y) << 16);
    v[1] = (unsigned)f2bf(a.z) | ((unsigned)f2bf(a.w) << 16);
    v[2] = (unsigned)f2bf(b.x) | ((unsigned)f2bf(b.y) << 16);
    v[3] = (unsigned)f2bf(b.z) | ((unsigned)f2bf(b.w) << 16);
    reinterpret_cast<uint4v*>(w_bf)[j] = v;
  } else if (i < NX8 + NWT8 + 2048) {
    int j = i - NX8 - NWT8;  // seed slot 0 from hx, tag 0
    float4 a = reinterpret_cast<const float4*>(hx)[j * 2];
    float4 b = reinterpret_cast<const float4*>(hx)[j * 2 + 1];
    uint4v v0, v1;
    v0[0] = f2bf(a.x); v0[1] = f2bf(a.y); v0[2] = f2bf(a.z); v0[3] = f2bf(a.w);
    v1[0] = f2bf(b.x); v1[1] = f2bf(b.y); v1[2] = f2bf(b.z); v1[3] = f2bf(b.w);
    unsigned int* p = h_tag + j * 8;
    store_x4_coherent(p, v0);
    store_x4_coherent(p + 4, v1);
  } else {
    int j = i - NX8 - NWT8 - 2048;  // clear slot 1
    unsigned int* p = h_tag + 16384 + j * 8;
    uint4v z = {0u, 0u, 0u, 0u};
    store_x4_coherent(p, z);
    store_x4_coherent(p + 4, z);
  }
}

// ---------------- Phase 2: gx GEMM ----------------
// 128x128 tile over rows r=b*2048+t, cols gcol. Epilogue writes
// gx[t][bg][nw][bq(4)][g(4)][jl(32)] bf16 (64B runs).
__global__ __launch_bounds__(256, 2) void gemm_gx(
    const unsigned short* __restrict__ x_bf, const unsigned short* __restrict__ w_bf,
    const float* __restrict__ b_ih, const float* __restrict__ b_hh,
    unsigned short* __restrict__ gx_ws) {
  __shared__ unsigned short As[128 * 40];
  __shared__ unsigned short Bs[128 * 40];
  __shared__ unsigned short Eg[128 * 136];
  const int bid = blockIdx.x;
  const int cb = bid & 15, rb = bid >> 4;
  const int r0 = rb * 128, c0 = cb * 128;
  const int tid = threadIdx.x;
  const int lane = tid & 63;
  const int w = tid >> 6;
  const int qr = (w >> 1) * 64, qc = (w & 1) * 64;
  f32x4 acc[4][4] = {};

  for (int kt = 0; kt < 16; ++kt) {
    const int k0 = kt * 32;
    uint4v av[2], bv[2];
#pragma unroll
    for (int c = 0; c < 2; ++c) {
      int flat = c * 256 + tid;
      int row = flat >> 2, q = flat & 3;
      av[c] = *reinterpret_cast<const uint4v*>(x_bf + (size_t)(r0 + row) * 512 + k0 + q * 8);
      bv[c] = *reinterpret_cast<const uint4v*>(w_bf + (size_t)(c0 + row) * 512 + k0 + q * 8);
    }
    __syncthreads();
#pragma unroll
    for (int c = 0; c < 2; ++c) {
      int flat = c * 256 + tid;
      int row = flat >> 2, q = flat & 3;
      *reinterpret_cast<uint4v*>(&As[row * 40 + q * 8]) = av[c];
      *reinterpret_cast<uint4v*>(&Bs[row * 40 + q * 8]) = bv[c];
    }
    __syncthreads();
    bf16x8 af[4], bfr[4];
#pragma unroll
    for (int mt = 0; mt < 4; ++mt)
      af[mt] = *reinterpret_cast<const bf16x8*>(&As[(qr + mt * 16 + (lane & 15)) * 40 + (lane >> 4) * 8]);
#pragma unroll
    for (int nt = 0; nt < 4; ++nt)
      bfr[nt] = *reinterpret_cast<const bf16x8*>(&Bs[(qc + nt * 16 + (lane & 15)) * 40 + (lane >> 4) * 8]);
#pragma unroll
    for (int mt = 0; mt < 4; ++mt)
#pragma unroll
      for (int nt = 0; nt < 4; ++nt)
        acc[mt][nt] = __builtin_amdgcn_mfma_f32_16x16x32_bf16(af[mt], bfr[nt], acc[mt][nt], 0, 0, 0);
  }
  __syncthreads();
#pragma unroll
  for (int nt = 0; nt < 4; ++nt) {
    int cg = c0 + qc + nt * 16 + (lane & 15);
    float bias = b_ih[cg] + b_hh[cg];
#pragma unroll
    for (int mt = 0; mt < 4; ++mt)
#pragma unroll
      for (int j = 0; j < 4; ++j) {
        int tr = qr + mt * 16 + (lane >> 4) * 4 + j;
        int cl = qc + nt * 16 + (lane & 15);
        Eg[tr * 136 + cl] = f2bf(acc[mt][nt][j] + bias);
      }
  }
  __syncthreads();
  const int b = r0 >> 11;          // batch, constant per tile
  const int g = c0 >> 9;           // gate, constant per tile
  const int t0 = r0 & 2047;
  const int nw0 = (c0 & 511) >> 5; // 4 col-groups per tile
  const int bg = b >> 2, bq = b & 3;
  for (int c = tid; c < 512; c += 256) {
    int tr = c >> 2, nwi = c & 3;
    size_t dst = (((size_t)(t0 + tr) * NBG + bg) * NCG + (nw0 + nwi)) * 512 + bq * 128 + g * 32;
    const unsigned short* src = &Eg[tr * 136 + nwi * 32];
#pragma unroll
    for (int q = 0; q < 4; ++q)
      *reinterpret_cast<uint4v*>(gx_ws + dst + q * 8) =
          *reinterpret_cast<const uint4v*>(src + q * 8);
  }
}

// ---------------- Phase 3: recurrence ----------------
// 128 WGs x 512 threads. WG (bg=bid&7, nw=bid>>3): h-cols [nw*32,+32),
// batches [bg*4,+4). bg = bid&7 -> sync domain on ONE XCD (round-robin
// dispatch heuristic; correctness covered by sc0sc1 fallback polls).
// Wave n = gi*2+half owns N-tile of 16 gate-cols with FULL K=512.
#define POLL_FAST() \
  asm volatile("global_load_dwordx4 %0, %1, off sc0" : "=v"(hv) : "v"(pollp))
#define POLL_SLOW() \
  asm volatile("global_load_dwordx4 %0, %1, off sc0 sc1" : "=v"(hv) : "v"(pollp))
#define VMWAIT(N) \
  do { asm volatile("s_waitcnt vmcnt(" #N ")" ::: "memory"); \
       __builtin_amdgcn_sched_barrier(0); } while (0)

__global__ __launch_bounds__(512) void lstm_rec(
    const float* __restrict__ cx, const float* __restrict__ w_hh,
    const unsigned short* __restrict__ gx_ws, unsigned int* __restrict__ h_tag,
    float* __restrict__ out) {
  const int bid = blockIdx.x;
  const int bg = bid & 7;    // batch-group == XCD (heuristic)
  const int nw = bid >> 3;   // col-group
  const int tid = threadIdx.x;
  const int lane = tid & 63;
  const int w = tid >> 6;
  const int gi = w >> 1;
  const int half = w & 1;
  __shared__ unsigned short As[4 * 536];   // h rows (bf16), stride 536
  __shared__ float Gt2[8 * 64];            // [n][cl*4+bq]
  __shared__ unsigned short GxL[2][512];   // gx dbuf [bq][g][jl]

  // cross-replay stale-line purge (L1+L2 invalidate), once
  __builtin_amdgcn_fence(__ATOMIC_ACQUIRE, "agent");

  // B-frags: one N-tile (16 gate-cols), full K=512 -> 16 frags = 64 VGPR
  bf16x8 breg[16];
  {
    int gcol = gi * 512 + nw * 32 + half * 16 + (lane & 15);
    const float* wrow = w_hh + (size_t)gcol * 512;
#pragma unroll
    for (int kk = 0; kk < 16; ++kk) {
      int k = kk * 32 + (lane >> 4) * 8;
      float4 f0 = *reinterpret_cast<const float4*>(wrow + k);
      float4 f1 = *reinterpret_cast<const float4*>(wrow + k + 4);
      uint4v v;
      v[0] = (unsigned)f2bf(f0.x) | ((unsigned)f2bf(f0.y) << 16);
      v[1] = (unsigned)f2bf(f0.z) | ((unsigned)f2bf(f0.w) << 16);
      v[2] = (unsigned)f2bf(f1.x) | ((unsigned)f2bf(f1.y) << 16);
      v[3] = (unsigned)f2bf(f1.z) | ((unsigned)f2bf(f1.w) << 16);
      breg[kk] = __builtin_bit_cast(bf16x8, v);
    }
  }
  // elementwise ownership (waves 0,1): bq=lane&3, cl=lane>>2, jl=w*16+cl
  const int bq = lane & 3;
  const int cl = lane >> 2;
  const int jl = (w & 1) * 16 + cl;
  const int col = nw * 32 + jl;
  const int bno = bg * 4 + bq;
  float c = 0.0f;
  if (w < 2) c = cx[bno * 512 + col];

  unsigned int* slot0 = h_tag;
  unsigned int* slot1 = h_tag + 16384;
  const unsigned int* pollp0 = slot0 + bg * 2048 + tid * 4;
  const unsigned int* pollp1 = slot1 + bg * 2048 + tid * 4;
  const unsigned short* gx_base = gx_ws + ((size_t)bg * NCG + nw) * 512;
  const size_t gx_tstride = (size_t)NBG * NCG * 512;

  uint4v hv;
  uint4v gxr;

  // ---- prologue: gx[0] + poll t=0 (tags seeded 0)
  if (w == 0)
    asm volatile("global_load_dwordx4 %0, %1, off"
                 : "=v"(gxr) : "v"(gx_base + lane * 8));
  {
    const unsigned int* pollp = pollp0;
    POLL_FAST();
    int guard = 0;
    for (;;) {
      VMWAIT(0);
      unsigned bad = (hv[0] >> 16) | (hv[1] >> 16) | (hv[2] >> 16) | (hv[3] >> 16);
      if (!bad || guard > (1 << 20)) break;
      if (++guard < 6) POLL_FAST(); else POLL_SLOW();
    }
    uint2v pk;
    pk[0] = (hv[0] & 0xffffu) | (hv[1] << 16);
    pk[1] = (hv[2] & 0xffffu) | (hv[3] << 16);
    *reinterpret_cast<uint2v*>(&As[(tid >> 7) * 536 + (tid & 127) * 4]) = pk;
  }
  if (w == 0)
    *reinterpret_cast<uint4v*>(&GxL[0][lane * 8]) = __builtin_bit_cast(uint4v, gxr);

  for (int t = 0; t < T_; ++t) {
    BARRIER_LGKM();  // A: As + GxL[t&1] ready
    const bool more = (t + 1 < T_);
    if (w == 0 && more)
      asm volatile("global_load_dwordx4 %0, %1, off"
                   : "=v"(gxr) : "v"(gx_base + (size_t)(t + 1) * gx_tstride + lane * 8));
    // ---- MFMA: full K=512, one N-tile per wave; 2 independent chains
    f32x4 a0 = {}, a1 = {};
#pragma unroll
    for (int kk = 0; kk < 16; kk += 2) {
      bf16x8 af0 = *reinterpret_cast<const bf16x8*>(
          &As[(lane & 3) * 536 + kk * 32 + (lane >> 4) * 8]);
      bf16x8 af1 = *reinterpret_cast<const bf16x8*>(
          &As[(lane & 3) * 536 + (kk + 1) * 32 + (lane >> 4) * 8]);
      a0 = __builtin_amdgcn_mfma_f32_16x16x32_bf16(af0, breg[kk], a0, 0, 0, 0);
      a1 = __builtin_amdgcn_mfma_f32_16x16x32_bf16(af1, breg[kk + 1], a1, 0, 0, 0);
    }
    if (lane < 16) {
      f32x4 s4 = a0 + a1;  // C rows 0-3 = batches 0-3, col = lane
      *reinterpret_cast<f32x4*>(&Gt2[w * 64 + lane * 4]) = s4;
    }
    BARRIER_LGKM();  // B: Gt2 complete
    const unsigned int* pollp = (t & 1) ? pollp0 : pollp1;
    if (w >= 2) {
      if (more) POLL_FAST();
    } else {
      // ---- elementwise (waves 0,1): 128 outputs, 4 LDS reads each
      const int gxb = t & 1;
      float s0 = Gt2[(0 * 2 + w) * 64 + lane] + bf2f(GxL[gxb][bq * 128 + 0 * 32 + jl]);
      float s1 = Gt2[(1 * 2 + w) * 64 + lane] + bf2f(GxL[gxb][bq * 128 + 1 * 32 + jl]);
      float s2 = Gt2[(2 * 2 + w) * 64 + lane] + bf2f(GxL[gxb][bq * 128 + 2 * 32 + jl]);
      float s3 = Gt2[(3 * 2 + w) * 64 + lane] + bf2f(GxL[gxb][bq * 128 + 3 * 32 + jl]);
      float ia = sigm(s0), fa = sigm(s1), ga = tanh_(s2), oa = sigm(s3);
      c = fa * c + ia * ga;
      float h = oa * tanh_(c);
      if (more) {  // publish first (critical path), then poll, then outs
        unsigned int word = (unsigned int)f2bf(h) | (((unsigned int)(t + 1)) << 16);
        unsigned int* pp = ((t & 1) ? slot0 : slot1) + bno * 512 + col;
        asm volatile("global_store_dword %0, %1, off sc0 sc1" :: "v"(pp), "v"(word) : "memory");
        POLL_FAST();
      }
      size_t bo = (size_t)bno * (T_ * H_) + (size_t)t * H_ + col;
      asm volatile("global_store_dword %0, %1, off" :: "v"(out + bo), "v"(fa) : "memory");
      asm volatile("global_store_dword %0, %1, off"
                   :: "v"(out + (size_t)B_ * T_ * H_ + bo), "v"(h) : "memory");
      asm volatile("global_store_dword %0, %1, off"
                   :: "v"(out + (size_t)2 * B_ * T_ * H_ + bo), "v"(ga) : "memory");
      if (!more) out[(size_t)3 * B_ * T_ * H_ + bno * 512 + col] = oa;
    }
    if (more) {
      // first wait: w<2 FIFO = [gxr?][pub][poll][out*3] -> vmcnt(3); w>=2: vmcnt(0)
      if (w < 2) VMWAIT(3); else VMWAIT(0);
      const unsigned want = (unsigned)(t + 1);
      unsigned bad = ((hv[0] >> 16) ^ want) | ((hv[1] >> 16) ^ want) |
                     ((hv[2] >> 16) ^ want) | ((hv[3] >> 16) ^ want);
      int guard = 0;
      while (bad) {
        if (++guard < 6) POLL_FAST(); else POLL_SLOW();
        VMWAIT(0);
        bad = ((hv[0] >> 16) ^ want) | ((hv[1] >> 16) ^ want) |
              ((hv[2] >> 16) ^ want) | ((hv[3] >> 16) ^ want);
        if (guard > (1 << 20)) break;
      }
      uint2v pk;
      pk[0] = (hv[0] & 0xffffu) | (hv[1] << 16);
      pk[1] = (hv[2] & 0xffffu) | (hv[3] << 16);
      *reinterpret_cast<uint2v*>(&As[(tid >> 7) * 536 + (tid & 127) * 4]) = pk;
      if (w == 0)
        *reinterpret_cast<uint4v*>(&GxL[(t + 1) & 1][lane * 8]) = __builtin_bit_cast(uint4v, gxr);
    }
  }
}

extern "C" void kernel_launch(void* const* d_in, const int* in_sizes, int n_in,
                              void* d_out, int out_size, void* d_ws, size_t ws_size,
                              hipStream_t stream) {
  const float* x    = (const float*)d_in[0];
  const float* hx   = (const float*)d_in[1];
  const float* cx   = (const float*)d_in[2];
  const float* w_ih = (const float*)d_in[3];
  const float* w_hh = (const float*)d_in[4];
  const float* b_ih = (const float*)d_in[5];
  const float* b_hh = (const float*)d_in[6];
  float* out = (float*)d_out;
  char* ws = (char*)d_ws;
  const size_t OFF_XBF  = 0;                    // 67,108,864
  const size_t OFF_WBF  = 67108864;             //  2,097,152
  const size_t OFF_GX   = 69206016;             // 268,435,456
  const size_t OFF_HTAG = 337641472;            //    131,072
  const size_t NEEDED   = 337772544;
  if (ws_size < NEEDED) return;

  unsigned short* x_bf  = (unsigned short*)(ws + OFF_XBF);
  unsigned short* w_bf  = (unsigned short*)(ws + OFF_WBF);
  unsigned short* gx_ws = (unsigned short*)(ws + OFF_GX);
  unsigned int*   h_tag = (unsigned int*)(ws + OFF_HTAG);

  prep_kernel<<<16912, 256, 0, stream>>>(x, w_ih, hx, x_bf, w_bf, h_tag);
  gemm_gx<<<8192, 256, 0, stream>>>(x_bf, w_bf, b_ih, b_hh, gx_ws);
  lstm_rec<<<128, 512, 0, stream>>>(cx, w_hh, gx_ws, h_tag, out);
}